// Round 3
// baseline (1379.540 us; speedup 1.0000x reference)
//
#include <hip/hip_runtime.h>

#define L 1024
#define DD 1024
#define BATCH 32
#define M_TOTAL (BATCH * L)  // 32768

typedef _Float16 f16;
typedef __attribute__((ext_vector_type(4))) _Float16 f16x4;
typedef __attribute__((ext_vector_type(8))) _Float16 f16x8;
typedef __attribute__((ext_vector_type(4))) float f32x4;

// async global->LDS, 16B per lane. LDS dest = wave-uniform base + lane*16.
__device__ __forceinline__ void load16_lds(const void* g, void* l) {
  __builtin_amdgcn_global_load_lds(
      (const __attribute__((address_space(1))) unsigned int*)g,
      (__attribute__((address_space(3))) unsigned int*)l,
      16, 0, 0);
}

// ---------------- small prep kernels ----------------

__global__ void gather_x_kernel(const int* __restrict__ positives,
                                const float* __restrict__ item_emb,
                                const float* __restrict__ pos_emb,
                                f16* __restrict__ x) {
  const int bl = blockIdx.x;
  const int lpos = bl & (L - 1);
  const int idx = positives[bl];
  const int d = threadIdx.x * 4;
  const float4 ie = *(const float4*)(item_emb + (size_t)idx * DD + d);
  const float4 pe = *(const float4*)(pos_emb + (size_t)lpos * DD + d);
  f16x4 h;
  h[0] = (f16)(ie.x + pe.x);
  h[1] = (f16)(ie.y + pe.y);
  h[2] = (f16)(ie.z + pe.z);
  h[3] = (f16)(ie.w + pe.w);
  *(f16x4*)(x + (size_t)bl * DD + d) = h;
}

__global__ void cast_w_kernel(const float* __restrict__ src, f16* __restrict__ dst) {
  const int i = (blockIdx.x * 256 + threadIdx.x) * 4;
  const float4 v = *(const float4*)(src + i);
  f16x4 h;
  h[0] = (f16)v.x; h[1] = (f16)v.y; h[2] = (f16)v.z; h[3] = (f16)v.w;
  *(f16x4*)(dst + i) = h;
}

// per-batch 1024x1024 f16 transpose via 64x64 LDS tiles
__global__ void transpose_v_kernel(const unsigned short* __restrict__ vin,
                                   unsigned short* __restrict__ vout) {
  const int b = blockIdx.z;
  const unsigned short* in = vin + (size_t)b * L * DD;
  unsigned short* out = vout + (size_t)b * L * DD;
  const int r0 = blockIdx.x * 64, c0 = blockIdx.y * 64;
  __shared__ unsigned short t[64][65];
  const int tid = threadIdx.x;
  for (int c = tid; c < 1024; c += 256) {
    const int r = c >> 4, cc = (c & 15) * 4;
    const ushort4 vv = *(const ushort4*)(in + (size_t)(r0 + r) * DD + c0 + cc);
    t[r][cc] = vv.x; t[r][cc + 1] = vv.y; t[r][cc + 2] = vv.z; t[r][cc + 3] = vv.w;
  }
  __syncthreads();
  for (int c = tid; c < 1024; c += 256) {
    const int r = c >> 4, cc = (c & 15) * 4;
    ushort4 vv;
    vv.x = t[cc][r]; vv.y = t[cc + 1][r]; vv.z = t[cc + 2][r]; vv.w = t[cc + 3][r];
    *(ushort4*)(out + (size_t)(c0 + r) * L + r0 + cc) = vv;
  }
}

// ---------------- shared 256x256 MFMA pipeline, 2 barriers / K-tile ----------------
// BK=64, 8 waves (2M x 4N), 512 threads, 128KB dynamic LDS double-buffer.
// AITER-style: 32 MFMA per barrier. Per tile:
//   read a0,bA,bB -> c0 -> read a1 -> c1 -> BARRIER -> stage(t+2) -> c2 -> c3
//   -> vmcnt(8) -> BARRIER
// Front-loaded ds_reads overlap LDS drain with MFMA; counted vmcnt keeps 16 loads
// in flight (never drains to 0 until the tail). Hazards:
//  - B region staged only after ALL waves' B reads returned (consumed by c0/c1
//    before the mid barrier) — stronger than the verified round-2 schedule.
//  - A region: a1 issued pre-barrier, drained under c1; stage-A write arrives
//    >=250cy after issue — same window as the verified phase-2/3 pattern.
//  - vmcnt(8): in flight = t+1's 8 + t+2's 8; waits for the oldest 8 (t+1).
// LDS layout per buf/mat: [chunk c=k/8][row][8 f16] -> conflict-free ds_read_b128
// (measured SQ_LDS_BANK_CONFLICT == 0 on this layout).

#define LDSOFF(d, mt, c, r) (((((d) * 2 + (mt)) * 8 + (c)) * 256 + (r)) * 8)

template <int LDAi, int LDBi>
__device__ __forceinline__ void pipeline256(
    const f16* __restrict__ Ag, const f16* __restrict__ Bg,
    f16* __restrict__ lds, f32x4 (&acc)[8][4],
    const int tid, const int nkt) {
  const int w = tid >> 6, l = tid & 63;
  const int wr = w >> 2, wc = w & 3;     // wave tile: rows wr*128+, cols wc*64+
  const int qd = l >> 4, mlo = l & 15;
  const int c1 = w >> 1, rbh = w & 1;    // staging task split

  auto stageA = [&](int dd, int h, int k0) {
    const int rb = h * 2 + rbh;
    load16_lds(Ag + (size_t)(rb * 64 + l) * LDAi + k0 + c1 * 8,
               lds + LDSOFF(dd, 0, c1, rb * 64));
    load16_lds(Ag + (size_t)(rb * 64 + l) * LDAi + k0 + (c1 + 4) * 8,
               lds + LDSOFF(dd, 0, c1 + 4, rb * 64));
  };
  auto stageB = [&](int dd, int h, int k0) {
    const int rb = h * 2 + rbh;
    load16_lds(Bg + (size_t)(rb * 64 + l) * LDBi + k0 + c1 * 8,
               lds + LDSOFF(dd, 1, c1, rb * 64));
    load16_lds(Bg + (size_t)(rb * 64 + l) * LDBi + k0 + (c1 + 4) * 8,
               lds + LDSOFF(dd, 1, c1 + 4, rb * 64));
  };

  // prologue: tile 0 fully (8 loads, oldest), then tile 1 fully (8 loads)
  stageA(0, 0, 0); stageA(0, 1, 0); stageB(0, 0, 0); stageB(0, 1, 0);
  asm volatile("" ::: "memory");  // keep t0 loads older than t1 loads
  stageA(1, 0, 64); stageA(1, 1, 64); stageB(1, 0, 64); stageB(1, 1, 64);
  asm volatile("s_waitcnt vmcnt(8)" ::: "memory");  // t0 landed; t1 (8) in flight
  __builtin_amdgcn_s_barrier();

#define LDA(mi, s) (*(const f16x8*)(lds + LDSOFF(d, 0, (s) * 4 + qd, wr * 128 + (mi) * 16 + mlo)))
#define LDB(ni, s) (*(const f16x8*)(lds + LDSOFF(d, 1, (s) * 4 + qd, wc * 64 + (ni) * 16 + mlo)))
#define MFMA16(a, b, c) __builtin_amdgcn_mfma_f32_16x16x32_f16(a, b, c, 0, 0, 0)

#pragma unroll 2
  for (int t = 0; t < nkt; ++t) {
    const int d = t & 1;
    const int k2 = (t + 2) * 64;
    const bool more = (t < nkt - 2);
    f16x8 a0[4][2], a1[4][2], bA[2][2], bB[2][2];
    // front-load reads: a0 (8 b128), bA (4), bB (4)
#pragma unroll
    for (int m = 0; m < 4; ++m) { a0[m][0] = LDA(m, 0); a0[m][1] = LDA(m, 1); }
#pragma unroll
    for (int n = 0; n < 2; ++n) { bA[n][0] = LDB(n, 0); bA[n][1] = LDB(n, 1); }
#pragma unroll
    for (int n = 0; n < 2; ++n) { bB[n][0] = LDB(n + 2, 0); bB[n][1] = LDB(n + 2, 1); }
    // ---- cluster 0: a0 x bA (16 MFMA); bB drains underneath
    __builtin_amdgcn_s_setprio(1);
#pragma unroll
    for (int m = 0; m < 4; ++m)
#pragma unroll
      for (int n = 0; n < 2; ++n) {
        acc[m][n] = MFMA16(a0[m][0], bA[n][0], acc[m][n]);
        acc[m][n] = MFMA16(a0[m][1], bA[n][1], acc[m][n]);
      }
    __builtin_amdgcn_s_setprio(0);
    // read a1 (8 b128) — drains under cluster 1
#pragma unroll
    for (int m = 0; m < 4; ++m) { a1[m][0] = LDA(m + 4, 0); a1[m][1] = LDA(m + 4, 1); }
    // ---- cluster 1: a0 x bB
    __builtin_amdgcn_s_setprio(1);
#pragma unroll
    for (int m = 0; m < 4; ++m)
#pragma unroll
      for (int n = 0; n < 2; ++n) {
        acc[m][n + 2] = MFMA16(a0[m][0], bB[n][0], acc[m][n + 2]);
        acc[m][n + 2] = MFMA16(a0[m][1], bB[n][1], acc[m][n + 2]);
      }
    __builtin_amdgcn_s_setprio(0);
    __builtin_amdgcn_s_barrier();  // all waves' B reads returned; a1 issued
    // stage tile t+2 into buf d (regions of tile t, now safe to overwrite)
    if (more) { stageB(d, 0, k2); stageB(d, 1, k2); stageA(d, 0, k2); stageA(d, 1, k2); }
    // ---- cluster 2: a1 x bA (stages interleave underneath)
    __builtin_amdgcn_s_setprio(1);
#pragma unroll
    for (int m = 0; m < 4; ++m)
#pragma unroll
      for (int n = 0; n < 2; ++n) {
        acc[m + 4][n] = MFMA16(a1[m][0], bA[n][0], acc[m + 4][n]);
        acc[m + 4][n] = MFMA16(a1[m][1], bA[n][1], acc[m + 4][n]);
      }
    __builtin_amdgcn_s_setprio(0);
    // ---- cluster 3: a1 x bB
    __builtin_amdgcn_s_setprio(1);
#pragma unroll
    for (int m = 0; m < 4; ++m)
#pragma unroll
      for (int n = 0; n < 2; ++n) {
        acc[m + 4][n + 2] = MFMA16(a1[m][0], bB[n][0], acc[m + 4][n + 2]);
        acc[m + 4][n + 2] = MFMA16(a1[m][1], bB[n][1], acc[m + 4][n + 2]);
      }
    __builtin_amdgcn_s_setprio(0);
    if (more) {
      asm volatile("s_waitcnt vmcnt(8)" ::: "memory");   // tile t+1 landed
    } else if (t == nkt - 2) {
      asm volatile("s_waitcnt vmcnt(0)" ::: "memory");   // drain for last tile
    }
    __builtin_amdgcn_s_barrier();
  }
#undef LDA
#undef LDB
#undef MFMA16
}

// ---------------- dense GEMM: C = A(MxK,ld 1024) * B^T (NxK, ld 1024) ----------------
// EPI 0: silu. EPI 1: (acc*gamma+beta)*scale with gn>=1024 -> (g1,b1).
template <int EPI, int NTN>  // NTN = N/256 (power of 2)
__global__ __launch_bounds__(512, 2) void gemm256_kernel(
    const f16* __restrict__ A, const f16* __restrict__ B, f16* __restrict__ Cout,
    const size_t ldA, const size_t ldC,
    const float* __restrict__ g0, const float* __restrict__ b0,
    const float* __restrict__ g1, const float* __restrict__ b1, const float scale) {
  extern __shared__ f16 lds[];  // [2 buf][2 mat][8 chunk][256 row][8] = 128KB
  const int bid = blockIdx.x;
  const int cpx = gridDim.x >> 3;                    // blocks per XCD (grid % 8 == 0)
  const int logical = (bid & 7) * cpx + (bid >> 3);  // contiguous range per XCD
  const int mt = logical / NTN, nt = logical % NTN;
  const int tm0 = mt * 256, tn0 = nt * 256;
  const int tid = threadIdx.x;

  f32x4 acc[8][4] = {};
  pipeline256<1024, 1024>(A + (size_t)tm0 * 1024, B + (size_t)tn0 * 1024, lds, acc, tid, 16);

  const int w = tid >> 6, l = tid & 63;
  const int wr = w >> 2, wc = w & 3;
  const int qd = l >> 4, mlo = l & 15;
#pragma unroll
  for (int i = 0; i < 8; ++i) {
#pragma unroll
    for (int j = 0; j < 4; ++j) {
      const int gn = tn0 + wc * 64 + j * 16 + mlo;
      float gg = 1.0f, bb = 0.0f;
      if (EPI == 1) {
        gg = (gn < 1024) ? g0[gn] : g1[gn - 1024];
        bb = (gn < 1024) ? b0[gn] : b1[gn - 1024];
      }
#pragma unroll
      for (int r = 0; r < 4; ++r) {
        const int gm = tm0 + wr * 128 + i * 16 + qd * 4 + r;
        float y = acc[i][j][r];
        if (EPI == 0) {
          y = y / (1.0f + __expf(-y));  // silu
        } else {
          y = (y * gg + bb) * scale;
        }
        Cout[(size_t)gm * ldC + gn] = (f16)y;
      }
    }
  }
}

// ---------------- QK^T 256x256 causal (masked, relu^2) -> P~ (f16) ----------------
// Active tiles: nt <= mt (10/batch), 320 blocks. q,k pre-scaled by 2^11 each =>
// acc = S*2^22. P~ = relu(acc*sparse_w)^2 masked. Diagonal tiles write masked
// zeros over the full 256x256 (pv reads cols < 256*(mt+1), all covered).
__global__ __launch_bounds__(512, 2) void qk256_kernel(
    const f16* __restrict__ QK,  // (32768 x 2048): cols [0,1024)=q~, [1024,2048)=k~
    const int* __restrict__ mask, const float* __restrict__ sparse_w,
    f16* __restrict__ P) {
  extern __shared__ f16 lds[];
  const int bid = blockIdx.x;
  const int logical = (bid & 7) * 40 + (bid >> 3);  // 40 = 320/8 blocks per XCD
  const int b = logical / 10;
  const int t10 = logical - b * 10;
  int mt, nt;
  if (t10 == 0)      { mt = 0; nt = 0; }
  else if (t10 <= 2) { mt = 1; nt = t10 - 1; }
  else if (t10 <= 5) { mt = 2; nt = t10 - 3; }
  else               { mt = 3; nt = t10 - 6; }
  const int tm0 = mt * 256, tn0 = nt * 256;
  const f16* Ag = QK + (size_t)b * L * 2048 + (size_t)tm0 * 2048;         // q~ rows
  const f16* Bg = QK + (size_t)b * L * 2048 + 1024 + (size_t)tn0 * 2048;  // k~ rows
  const int tid = threadIdx.x;

  f32x4 acc[8][4] = {};
  pipeline256<2048, 2048>(Ag, Bg, lds, acc, tid, 16);

  const int w = tid >> 6, l = tid & 63;
  const int wr = w >> 2, wc = w & 3;
  const int qd = l >> 4, mlo = l & 15;
  const int* mb = mask + b * L;
  f16* Pb = P + (size_t)b * L * L;
#pragma unroll
  for (int i = 0; i < 8; ++i) {
#pragma unroll
    for (int j = 0; j < 4; ++j) {
      const int gk = tn0 + wc * 64 + j * 16 + mlo;
      const int mk = mb[gk];
#pragma unroll
      for (int r = 0; r < 4; ++r) {
        const int gq = tm0 + wr * 128 + i * 16 + qd * 4 + r;
        float p = 0.0f;
        const bool blocked = (gk > gq) || ((gk != gq) && (mk == 0));
        if (!blocked) {
          p = acc[i][j][r] * sparse_w[(size_t)gq * L + gk];
          p = fmaxf(p, 0.0f);
          p = p * p;
        }
        Pb[(size_t)gq * L + gk] = (f16)p;
      }
    }
  }
}

// ---------------- PV 256x256: out = (P~ @ V) * 2^-64, f32 out ----------------
// kmax = 256*(mt+1) (causal, rounded to tile); nkt = 4*(mt+1) in {4,8,12,16}.
__global__ __launch_bounds__(512, 2) void pv256_kernel(
    const f16* __restrict__ P, const f16* __restrict__ Vt, float* __restrict__ Out) {
  extern __shared__ f16 lds[];
  const int bid = blockIdx.x;
  const int logical = (bid & 7) * 64 + (bid >> 3);  // 64 = 512/8 blocks per XCD
  const int b = logical >> 4;
  const int tile = logical & 15;
  const int mt = tile >> 2, nt = tile & 3;
  const int tm0 = mt * 256, tn0 = nt * 256;
  const f16* Ag = P + (size_t)b * L * L + (size_t)tm0 * L;    // P~ rows
  const f16* Bg = Vt + (size_t)b * L * DD + (size_t)tn0 * L;  // Vt rows (d-major)
  const int tid = threadIdx.x;

  f32x4 acc[8][4] = {};
  pipeline256<L, L>(Ag, Bg, lds, acc, tid, (mt + 1) * 4);

  const int w = tid >> 6, l = tid & 63;
  const int wr = w >> 2, wc = w & 3;
  const int qd = l >> 4, mlo = l & 15;
  float* outb = Out + (size_t)b * L * DD;
  const float fin = 5.421010862427522e-20f;  // 2^-64 = 2^-44 (qk scales) * 2^-20 (1/(L*D))
#pragma unroll
  for (int i = 0; i < 8; ++i) {
#pragma unroll
    for (int j = 0; j < 4; ++j) {
#pragma unroll
      for (int r = 0; r < 4; ++r) {
        const int gq = tm0 + wr * 128 + i * 16 + qd * 4 + r;
        const int gd = tn0 + wc * 64 + j * 16 + mlo;
        outb[(size_t)gq * DD + gd] = acc[i][j][r] * fin;
      }
    }
  }
}

// ---------------- launch ----------------
extern "C" void kernel_launch(void* const* d_in, const int* in_sizes, int n_in,
                              void* d_out, int out_size, void* d_ws, size_t ws_size,
                              hipStream_t stream) {
  const int* positives = (const int*)d_in[0];
  const int* mask = (const int*)d_in[1];
  const float* item_emb = (const float*)d_in[2];
  const float* pos_emb = (const float*)d_in[3];
  const float* Wz = (const float*)d_in[4];
  const float* Wv = (const float*)d_in[5];
  const float* Wq = (const float*)d_in[6];
  const float* Wk = (const float*)d_in[7];
  const float* gamma_q = (const float*)d_in[8];   // (2,L) -> head 0 = first L
  const float* beta_q = (const float*)d_in[9];
  const float* gamma_k = (const float*)d_in[10];
  const float* beta_k = (const float*)d_in[11];
  const float* sparse_w = (const float*)d_in[12];
  float* out = (float*)d_out;

  char* ws = (char*)d_ws;
  const size_t MB = 1024 * 1024;
  // layout (peak 264MB, known-good):
  //  [0,2)   Wzh      [2,4)  Wvh      [4,8)  Wqkh (stacked 2048x1024)
  //  [8,72)  bufZ: z, later vT
  //  [72,136) bufV: v, later P~
  //  [136,264) bufQK: x (first 64MB, dead after v-gemm), then q~|k~ (128MB)
  f16* Wzh = (f16*)(ws + 0 * MB);
  f16* Wvh = (f16*)(ws + 2 * MB);
  f16* Wqkh = (f16*)(ws + 4 * MB);
  f16* bufZ = (f16*)(ws + 8 * MB);
  f16* bufV = (f16*)(ws + 72 * MB);
  f16* bufQK = (f16*)(ws + 136 * MB);
  f16* bufX = bufQK;  // x occupies first 64MB of QK region until overwritten

  // opt-in to 128KB dynamic LDS (one-time; clear sticky state)
  static bool attr_set = false;
  if (!attr_set) {
    hipFuncSetAttribute(reinterpret_cast<const void*>(gemm256_kernel<0, 4>),
                        hipFuncAttributeMaxDynamicSharedMemorySize, 131072);
    hipFuncSetAttribute(reinterpret_cast<const void*>(gemm256_kernel<1, 8>),
                        hipFuncAttributeMaxDynamicSharedMemorySize, 131072);
    hipFuncSetAttribute(reinterpret_cast<const void*>(qk256_kernel),
                        hipFuncAttributeMaxDynamicSharedMemorySize, 131072);
    hipFuncSetAttribute(reinterpret_cast<const void*>(pv256_kernel),
                        hipFuncAttributeMaxDynamicSharedMemorySize, 131072);
    (void)hipGetLastError();
    attr_set = true;
  }

  cast_w_kernel<<<1024, 256, 0, stream>>>(Wz, Wzh);
  cast_w_kernel<<<1024, 256, 0, stream>>>(Wv, Wvh);
  cast_w_kernel<<<1024, 256, 0, stream>>>(Wq, Wqkh);             // rows [0,1024)
  cast_w_kernel<<<1024, 256, 0, stream>>>(Wk, Wqkh + 1024 * 1024);  // rows [1024,2048)
  gather_x_kernel<<<M_TOTAL, 256, 0, stream>>>(positives, item_emb, pos_emb, bufX);

  // z = silu(x Wz^T), v = silu(x Wv^T): 128 m-tiles x 4 n-tiles = 512 blocks
  gemm256_kernel<0, 4><<<512, 512, 131072, stream>>>(
      bufX, Wzh, bufZ, 1024, 1024, nullptr, nullptr, nullptr, nullptr, 1.0f);
  gemm256_kernel<0, 4><<<512, 512, 131072, stream>>>(
      bufX, Wvh, bufV, 1024, 1024, nullptr, nullptr, nullptr, nullptr, 1.0f);
  // [q~|k~] = (z [Wq;Wk]^T * gamma + beta) * 2^11 -> bufQK (overwrites dead x)
  gemm256_kernel<1, 8><<<1024, 512, 131072, stream>>>(
      bufZ, Wqkh, bufQK, 1024, 2048, gamma_q, beta_q, gamma_k, beta_k, 2048.0f);
  // vT (overwrites z in bufZ — safe: qk-proj already consumed z, stream-ordered)
  const dim3 gt(16, 16, BATCH);
  transpose_v_kernel<<<gt, 256, 0, stream>>>((const unsigned short*)bufV, (unsigned short*)bufZ);
  // P~ = relu(S~ * sparse_w)^2 masked, 256^2 causal tiles (overwrites v in bufV)
  qk256_kernel<<<320, 512, 131072, stream>>>(bufQK, mask, sparse_w, bufV);
  // out = (P~ @ V) * 2^-64, 256^2 tiles
  pv256_kernel<<<512, 512, 131072, stream>>>(bufV, bufZ, out);
}

// Round 4
// 998.013 us; speedup vs baseline: 1.3823x; 1.3823x over previous
//
#include <hip/hip_runtime.h>

#define L 1024
#define DD 1024
#define BATCH 32
#define M_TOTAL (BATCH * L)  // 32768

typedef _Float16 f16;
typedef __attribute__((ext_vector_type(4))) _Float16 f16x4;
typedef __attribute__((ext_vector_type(8))) _Float16 f16x8;
typedef __attribute__((ext_vector_type(4))) float f32x4;

// async global->LDS, 16B per lane. LDS dest = wave-uniform base + lane*16.
__device__ __forceinline__ void load16_lds(const void* g, void* l) {
  __builtin_amdgcn_global_load_lds(
      (const __attribute__((address_space(1))) unsigned int*)g,
      (__attribute__((address_space(3))) unsigned int*)l,
      16, 0, 0);
}

// ---------------- small prep kernels ----------------

__global__ void gather_x_kernel(const int* __restrict__ positives,
                                const float* __restrict__ item_emb,
                                const float* __restrict__ pos_emb,
                                f16* __restrict__ x) {
  const int bl = blockIdx.x;
  const int lpos = bl & (L - 1);
  const int idx = positives[bl];
  const int d = threadIdx.x * 4;
  const float4 ie = *(const float4*)(item_emb + (size_t)idx * DD + d);
  const float4 pe = *(const float4*)(pos_emb + (size_t)lpos * DD + d);
  f16x4 h;
  h[0] = (f16)(ie.x + pe.x);
  h[1] = (f16)(ie.y + pe.y);
  h[2] = (f16)(ie.z + pe.z);
  h[3] = (f16)(ie.w + pe.w);
  *(f16x4*)(x + (size_t)bl * DD + d) = h;
}

__global__ void cast_w_kernel(const float* __restrict__ src, f16* __restrict__ dst) {
  const int i = (blockIdx.x * 256 + threadIdx.x) * 4;
  const float4 v = *(const float4*)(src + i);
  f16x4 h;
  h[0] = (f16)v.x; h[1] = (f16)v.y; h[2] = (f16)v.z; h[3] = (f16)v.w;
  *(f16x4*)(dst + i) = h;
}

// per-batch 1024x1024 f16 transpose via 64x64 LDS tiles
__global__ void transpose_v_kernel(const unsigned short* __restrict__ vin,
                                   unsigned short* __restrict__ vout) {
  const int b = blockIdx.z;
  const unsigned short* in = vin + (size_t)b * L * DD;
  unsigned short* out = vout + (size_t)b * L * DD;
  const int r0 = blockIdx.x * 64, c0 = blockIdx.y * 64;
  __shared__ unsigned short t[64][65];
  const int tid = threadIdx.x;
  for (int c = tid; c < 1024; c += 256) {
    const int r = c >> 4, cc = (c & 15) * 4;
    const ushort4 vv = *(const ushort4*)(in + (size_t)(r0 + r) * DD + c0 + cc);
    t[r][cc] = vv.x; t[r][cc + 1] = vv.y; t[r][cc + 2] = vv.z; t[r][cc + 3] = vv.w;
  }
  __syncthreads();
  for (int c = tid; c < 1024; c += 256) {
    const int r = c >> 4, cc = (c & 15) * 4;
    ushort4 vv;
    vv.x = t[cc][r]; vv.y = t[cc + 1][r]; vv.z = t[cc + 2][r]; vv.w = t[cc + 3][r];
    *(ushort4*)(out + (size_t)(c0 + r) * L + r0 + cc) = vv;
  }
}

// ---------------- shared 256x256 MFMA pipeline, 3 barriers / K-tile ----------------
// BK=64, 8 waves (2M x 4N), 512 threads, 128KB dynamic LDS double-buffer.
// Spill-free variant of the 2-barrier schedule: fragment liveness capped at 64
// VGPRs (a0+bA+bB, then a1+bA+bB — never a0 and a1 together), matching the
// verified round-2 peak. Per tile:
//   read a0,bA,bB -> c0:a0xbA -> c1:a0xbB (a0 dies)
//   BARRIER1 -> stageB(t+2)   [B region consumed by all waves via MFMA dataflow]
//   read a1 -> lgkmcnt(0)
//   BARRIER2 -> stageA(t+2)   [all waves' a1 in regs before any A write lands]
//   c2:a1xbA -> c3:a1xbB -> vmcnt(8) -> BARRIER3
// Counted vmcnt: 16 loads in flight steady-state; vmcnt(8) confirms tile t+1.
// LDS layout per buf/mat: [chunk c=k/8][row][8 f16] -> conflict-free ds_read_b128
// (measured SQ_LDS_BANK_CONFLICT == 0 on this layout).

#define LDSOFF(d, mt, c, r) (((((d) * 2 + (mt)) * 8 + (c)) * 256 + (r)) * 8)

template <int LDAi, int LDBi>
__device__ __forceinline__ void pipeline256(
    const f16* __restrict__ Ag, const f16* __restrict__ Bg,
    f16* __restrict__ lds, f32x4 (&acc)[8][4],
    const int tid, const int nkt) {
  const int w = tid >> 6, l = tid & 63;
  const int wr = w >> 2, wc = w & 3;     // wave tile: rows wr*128+, cols wc*64+
  const int qd = l >> 4, mlo = l & 15;
  const int c1 = w >> 1, rbh = w & 1;    // staging task split

  auto stageA = [&](int dd, int h, int k0) {
    const int rb = h * 2 + rbh;
    load16_lds(Ag + (size_t)(rb * 64 + l) * LDAi + k0 + c1 * 8,
               lds + LDSOFF(dd, 0, c1, rb * 64));
    load16_lds(Ag + (size_t)(rb * 64 + l) * LDAi + k0 + (c1 + 4) * 8,
               lds + LDSOFF(dd, 0, c1 + 4, rb * 64));
  };
  auto stageB = [&](int dd, int h, int k0) {
    const int rb = h * 2 + rbh;
    load16_lds(Bg + (size_t)(rb * 64 + l) * LDBi + k0 + c1 * 8,
               lds + LDSOFF(dd, 1, c1, rb * 64));
    load16_lds(Bg + (size_t)(rb * 64 + l) * LDBi + k0 + (c1 + 4) * 8,
               lds + LDSOFF(dd, 1, c1 + 4, rb * 64));
  };

  // prologue: tile 0 fully (8 loads, oldest), then tile 1 fully (8 loads)
  stageA(0, 0, 0); stageA(0, 1, 0); stageB(0, 0, 0); stageB(0, 1, 0);
  asm volatile("" ::: "memory");  // keep t0 loads older than t1 loads
  stageA(1, 0, 64); stageA(1, 1, 64); stageB(1, 0, 64); stageB(1, 1, 64);
  asm volatile("s_waitcnt vmcnt(8)" ::: "memory");  // t0 landed; t1 (8) in flight
  __builtin_amdgcn_s_barrier();

#define LDA(mi, s) (*(const f16x8*)(lds + LDSOFF(d, 0, (s) * 4 + qd, wr * 128 + (mi) * 16 + mlo)))
#define LDB(ni, s) (*(const f16x8*)(lds + LDSOFF(d, 1, (s) * 4 + qd, wc * 64 + (ni) * 16 + mlo)))
#define MFMA16(a, b, c) __builtin_amdgcn_mfma_f32_16x16x32_f16(a, b, c, 0, 0, 0)

#pragma unroll 2
  for (int t = 0; t < nkt; ++t) {
    const int d = t & 1;
    const int k2 = (t + 2) * 64;
    const bool more = (t < nkt - 2);
    f16x8 a0[4][2], a1[4][2], bA[2][2], bB[2][2];
    // front-load reads: a0 (8 b128), bA (4), bB (4) -> 64 VGPRs of fragments
#pragma unroll
    for (int m = 0; m < 4; ++m) { a0[m][0] = LDA(m, 0); a0[m][1] = LDA(m, 1); }
#pragma unroll
    for (int n = 0; n < 2; ++n) { bA[n][0] = LDB(n, 0); bA[n][1] = LDB(n, 1); }
#pragma unroll
    for (int n = 0; n < 2; ++n) { bB[n][0] = LDB(n + 2, 0); bB[n][1] = LDB(n + 2, 1); }
    // ---- cluster 0: a0 x bA (16 MFMA); bB drains underneath
    __builtin_amdgcn_s_setprio(1);
#pragma unroll
    for (int m = 0; m < 4; ++m)
#pragma unroll
      for (int n = 0; n < 2; ++n) {
        acc[m][n] = MFMA16(a0[m][0], bA[n][0], acc[m][n]);
        acc[m][n] = MFMA16(a0[m][1], bA[n][1], acc[m][n]);
      }
    __builtin_amdgcn_s_setprio(0);
    // ---- cluster 1: a0 x bB (a0 dies after this)
    __builtin_amdgcn_s_setprio(1);
#pragma unroll
    for (int m = 0; m < 4; ++m)
#pragma unroll
      for (int n = 0; n < 2; ++n) {
        acc[m][n + 2] = MFMA16(a0[m][0], bB[n][0], acc[m][n + 2]);
        acc[m][n + 2] = MFMA16(a0[m][1], bB[n][1], acc[m][n + 2]);
      }
    __builtin_amdgcn_s_setprio(0);
    __builtin_amdgcn_s_barrier();  // B region + a0 consumed by all waves
    // stage B(t+2) into buf d (B region of tile t now dead everywhere)
    if (more) { stageB(d, 0, k2); stageB(d, 1, k2); }
    // read a1 from buf d's A region (not yet overwritten); peak live = 64
#pragma unroll
    for (int m = 0; m < 4; ++m) { a1[m][0] = LDA(m + 4, 0); a1[m][1] = LDA(m + 4, 1); }
    asm volatile("s_waitcnt lgkmcnt(0)" ::: "memory");  // a1 in regs
    __builtin_amdgcn_s_barrier();  // all waves drained their a1 reads
    // stage A(t+2) into buf d (A region now dead everywhere)
    if (more) { stageA(d, 0, k2); stageA(d, 1, k2); }
    // ---- cluster 2: a1 x bA
    __builtin_amdgcn_s_setprio(1);
#pragma unroll
    for (int m = 0; m < 4; ++m)
#pragma unroll
      for (int n = 0; n < 2; ++n) {
        acc[m + 4][n] = MFMA16(a1[m][0], bA[n][0], acc[m + 4][n]);
        acc[m + 4][n] = MFMA16(a1[m][1], bA[n][1], acc[m + 4][n]);
      }
    __builtin_amdgcn_s_setprio(0);
    // ---- cluster 3: a1 x bB
    __builtin_amdgcn_s_setprio(1);
#pragma unroll
    for (int m = 0; m < 4; ++m)
#pragma unroll
      for (int n = 0; n < 2; ++n) {
        acc[m + 4][n + 2] = MFMA16(a1[m][0], bB[n][0], acc[m + 4][n + 2]);
        acc[m + 4][n + 2] = MFMA16(a1[m][1], bB[n][1], acc[m + 4][n + 2]);
      }
    __builtin_amdgcn_s_setprio(0);
    if (more) {
      asm volatile("s_waitcnt vmcnt(8)" ::: "memory");   // tile t+1 landed
    } else if (t == nkt - 2) {
      asm volatile("s_waitcnt vmcnt(0)" ::: "memory");   // drain for last tile
    }
    __builtin_amdgcn_s_barrier();
  }
#undef LDA
#undef LDB
#undef MFMA16
}

// ---------------- dense GEMM: C = A(MxK,ld 1024) * B^T (NxK, ld 1024) ----------------
// EPI 0: silu. EPI 1: (acc*gamma+beta)*scale with gn>=1024 -> (g1,b1).
template <int EPI, int NTN>  // NTN = N/256 (power of 2)
__global__ __launch_bounds__(512, 2) void gemm256_kernel(
    const f16* __restrict__ A, const f16* __restrict__ B, f16* __restrict__ Cout,
    const size_t ldA, const size_t ldC,
    const float* __restrict__ g0, const float* __restrict__ b0,
    const float* __restrict__ g1, const float* __restrict__ b1, const float scale) {
  extern __shared__ f16 lds[];  // [2 buf][2 mat][8 chunk][256 row][8] = 128KB
  const int bid = blockIdx.x;
  const int cpx = gridDim.x >> 3;                    // blocks per XCD (grid % 8 == 0)
  const int logical = (bid & 7) * cpx + (bid >> 3);  // contiguous range per XCD
  const int mt = logical / NTN, nt = logical % NTN;
  const int tm0 = mt * 256, tn0 = nt * 256;
  const int tid = threadIdx.x;

  f32x4 acc[8][4] = {};
  pipeline256<1024, 1024>(A + (size_t)tm0 * 1024, B + (size_t)tn0 * 1024, lds, acc, tid, 16);

  const int w = tid >> 6, l = tid & 63;
  const int wr = w >> 2, wc = w & 3;
  const int qd = l >> 4, mlo = l & 15;
#pragma unroll
  for (int i = 0; i < 8; ++i) {
#pragma unroll
    for (int j = 0; j < 4; ++j) {
      const int gn = tn0 + wc * 64 + j * 16 + mlo;
      float gg = 1.0f, bb = 0.0f;
      if (EPI == 1) {
        gg = (gn < 1024) ? g0[gn] : g1[gn - 1024];
        bb = (gn < 1024) ? b0[gn] : b1[gn - 1024];
      }
#pragma unroll
      for (int r = 0; r < 4; ++r) {
        const int gm = tm0 + wr * 128 + i * 16 + qd * 4 + r;
        float y = acc[i][j][r];
        if (EPI == 0) {
          y = y / (1.0f + __expf(-y));  // silu
        } else {
          y = (y * gg + bb) * scale;
        }
        Cout[(size_t)gm * ldC + gn] = (f16)y;
      }
    }
  }
}

// ---------------- QK^T 256x256 causal (masked, relu^2) -> P~ (f16) ----------------
// Active tiles: nt <= mt (10/batch), 320 blocks. q,k pre-scaled by 2^11 each =>
// acc = S*2^22. P~ = relu(acc*sparse_w)^2 masked. Diagonal tiles write masked
// zeros over the full 256x256 (pv reads cols < 256*(mt+1), all covered).
__global__ __launch_bounds__(512, 2) void qk256_kernel(
    const f16* __restrict__ QK,  // (32768 x 2048): cols [0,1024)=q~, [1024,2048)=k~
    const int* __restrict__ mask, const float* __restrict__ sparse_w,
    f16* __restrict__ P) {
  extern __shared__ f16 lds[];
  const int bid = blockIdx.x;
  const int logical = (bid & 7) * 40 + (bid >> 3);  // 40 = 320/8 blocks per XCD
  const int b = logical / 10;
  const int t10 = logical - b * 10;
  int mt, nt;
  if (t10 == 0)      { mt = 0; nt = 0; }
  else if (t10 <= 2) { mt = 1; nt = t10 - 1; }
  else if (t10 <= 5) { mt = 2; nt = t10 - 3; }
  else               { mt = 3; nt = t10 - 6; }
  const int tm0 = mt * 256, tn0 = nt * 256;
  const f16* Ag = QK + (size_t)b * L * 2048 + (size_t)tm0 * 2048;         // q~ rows
  const f16* Bg = QK + (size_t)b * L * 2048 + 1024 + (size_t)tn0 * 2048;  // k~ rows
  const int tid = threadIdx.x;

  f32x4 acc[8][4] = {};
  pipeline256<2048, 2048>(Ag, Bg, lds, acc, tid, 16);

  const int w = tid >> 6, l = tid & 63;
  const int wr = w >> 2, wc = w & 3;
  const int qd = l >> 4, mlo = l & 15;
  const int* mb = mask + b * L;
  f16* Pb = P + (size_t)b * L * L;
#pragma unroll
  for (int i = 0; i < 8; ++i) {
#pragma unroll
    for (int j = 0; j < 4; ++j) {
      const int gk = tn0 + wc * 64 + j * 16 + mlo;
      const int mk = mb[gk];
#pragma unroll
      for (int r = 0; r < 4; ++r) {
        const int gq = tm0 + wr * 128 + i * 16 + qd * 4 + r;
        float p = 0.0f;
        const bool blocked = (gk > gq) || ((gk != gq) && (mk == 0));
        if (!blocked) {
          p = acc[i][j][r] * sparse_w[(size_t)gq * L + gk];
          p = fmaxf(p, 0.0f);
          p = p * p;
        }
        Pb[(size_t)gq * L + gk] = (f16)p;
      }
    }
  }
}

// ---------------- PV 256x256: out = (P~ @ V) * 2^-64, f32 out ----------------
// kmax = 256*(mt+1) (causal, rounded to tile); nkt = 4*(mt+1) in {4,8,12,16}.
__global__ __launch_bounds__(512, 2) void pv256_kernel(
    const f16* __restrict__ P, const f16* __restrict__ Vt, float* __restrict__ Out) {
  extern __shared__ f16 lds[];
  const int bid = blockIdx.x;
  const int logical = (bid & 7) * 64 + (bid >> 3);  // 64 = 512/8 blocks per XCD
  const int b = logical >> 4;
  const int tile = logical & 15;
  const int mt = tile >> 2, nt = tile & 3;
  const int tm0 = mt * 256, tn0 = nt * 256;
  const f16* Ag = P + (size_t)b * L * L + (size_t)tm0 * L;    // P~ rows
  const f16* Bg = Vt + (size_t)b * L * DD + (size_t)tn0 * L;  // Vt rows (d-major)
  const int tid = threadIdx.x;

  f32x4 acc[8][4] = {};
  pipeline256<L, L>(Ag, Bg, lds, acc, tid, (mt + 1) * 4);

  const int w = tid >> 6, l = tid & 63;
  const int wr = w >> 2, wc = w & 3;
  const int qd = l >> 4, mlo = l & 15;
  float* outb = Out + (size_t)b * L * DD;
  const float fin = 5.421010862427522e-20f;  // 2^-64 = 2^-44 (qk scales) * 2^-20 (1/(L*D))
#pragma unroll
  for (int i = 0; i < 8; ++i) {
#pragma unroll
    for (int j = 0; j < 4; ++j) {
#pragma unroll
      for (int r = 0; r < 4; ++r) {
        const int gq = tm0 + wr * 128 + i * 16 + qd * 4 + r;
        const int gd = tn0 + wc * 64 + j * 16 + mlo;
        outb[(size_t)gq * DD + gd] = acc[i][j][r] * fin;
      }
    }
  }
}

// ---------------- launch ----------------
extern "C" void kernel_launch(void* const* d_in, const int* in_sizes, int n_in,
                              void* d_out, int out_size, void* d_ws, size_t ws_size,
                              hipStream_t stream) {
  const int* positives = (const int*)d_in[0];
  const int* mask = (const int*)d_in[1];
  const float* item_emb = (const float*)d_in[2];
  const float* pos_emb = (const float*)d_in[3];
  const float* Wz = (const float*)d_in[4];
  const float* Wv = (const float*)d_in[5];
  const float* Wq = (const float*)d_in[6];
  const float* Wk = (const float*)d_in[7];
  const float* gamma_q = (const float*)d_in[8];   // (2,L) -> head 0 = first L
  const float* beta_q = (const float*)d_in[9];
  const float* gamma_k = (const float*)d_in[10];
  const float* beta_k = (const float*)d_in[11];
  const float* sparse_w = (const float*)d_in[12];
  float* out = (float*)d_out;

  char* ws = (char*)d_ws;
  const size_t MB = 1024 * 1024;
  // layout (peak 264MB, known-good):
  //  [0,2)   Wzh      [2,4)  Wvh      [4,8)  Wqkh (stacked 2048x1024)
  //  [8,72)  bufZ: z, later vT
  //  [72,136) bufV: v, later P~
  //  [136,264) bufQK: x (first 64MB, dead after v-gemm), then q~|k~ (128MB)
  f16* Wzh = (f16*)(ws + 0 * MB);
  f16* Wvh = (f16*)(ws + 2 * MB);
  f16* Wqkh = (f16*)(ws + 4 * MB);
  f16* bufZ = (f16*)(ws + 8 * MB);
  f16* bufV = (f16*)(ws + 72 * MB);
  f16* bufQK = (f16*)(ws + 136 * MB);
  f16* bufX = bufQK;  // x occupies first 64MB of QK region until overwritten

  // opt-in to 128KB dynamic LDS (one-time; clear sticky state)
  static bool attr_set = false;
  if (!attr_set) {
    hipFuncSetAttribute(reinterpret_cast<const void*>(gemm256_kernel<0, 4>),
                        hipFuncAttributeMaxDynamicSharedMemorySize, 131072);
    hipFuncSetAttribute(reinterpret_cast<const void*>(gemm256_kernel<1, 8>),
                        hipFuncAttributeMaxDynamicSharedMemorySize, 131072);
    hipFuncSetAttribute(reinterpret_cast<const void*>(qk256_kernel),
                        hipFuncAttributeMaxDynamicSharedMemorySize, 131072);
    hipFuncSetAttribute(reinterpret_cast<const void*>(pv256_kernel),
                        hipFuncAttributeMaxDynamicSharedMemorySize, 131072);
    (void)hipGetLastError();
    attr_set = true;
  }

  cast_w_kernel<<<1024, 256, 0, stream>>>(Wz, Wzh);
  cast_w_kernel<<<1024, 256, 0, stream>>>(Wv, Wvh);
  cast_w_kernel<<<1024, 256, 0, stream>>>(Wq, Wqkh);             // rows [0,1024)
  cast_w_kernel<<<1024, 256, 0, stream>>>(Wk, Wqkh + 1024 * 1024);  // rows [1024,2048)
  gather_x_kernel<<<M_TOTAL, 256, 0, stream>>>(positives, item_emb, pos_emb, bufX);

  // z = silu(x Wz^T), v = silu(x Wv^T): 128 m-tiles x 4 n-tiles = 512 blocks
  gemm256_kernel<0, 4><<<512, 512, 131072, stream>>>(
      bufX, Wzh, bufZ, 1024, 1024, nullptr, nullptr, nullptr, nullptr, 1.0f);
  gemm256_kernel<0, 4><<<512, 512, 131072, stream>>>(
      bufX, Wvh, bufV, 1024, 1024, nullptr, nullptr, nullptr, nullptr, 1.0f);
  // [q~|k~] = (z [Wq;Wk]^T * gamma + beta) * 2^11 -> bufQK (overwrites dead x)
  gemm256_kernel<1, 8><<<1024, 512, 131072, stream>>>(
      bufZ, Wqkh, bufQK, 1024, 2048, gamma_q, beta_q, gamma_k, beta_k, 2048.0f);
  // vT (overwrites z in bufZ — safe: qk-proj already consumed z, stream-ordered)
  const dim3 gt(16, 16, BATCH);
  transpose_v_kernel<<<gt, 256, 0, stream>>>((const unsigned short*)bufV, (unsigned short*)bufZ);
  // P~ = relu(S~ * sparse_w)^2 masked, 256^2 causal tiles (overwrites v in bufV)
  qk256_kernel<<<320, 512, 131072, stream>>>(bufQK, mask, sparse_w, bufV);
  // out = (P~ @ V) * 2^-64, 256^2 tiles
  pv256_kernel<<<512, 512, 131072, stream>>>(bufV, bufZ, out);
}